// Round 13
// baseline (179.800 us; speedup 1.0000x reference)
//
#include <hip/hip_runtime.h>

#define N_NODES 100000
#define N_EDGES 1600000
#define NQUAD (N_EDGES / 4)      // 400000
#define NEG_SLOPE 0.2f

#define NBKT 512                 // dst buckets (510 populated + tail)
#define BDIV 196                 // nodes per bucket
#define NUSED 511                // bucket blocks launched
#define PB 500                   // partition blocks
#define QPB (NQUAD / PB)         // 800 quads = 3200 edges per partition block
#define PBS 512                  // histT/offT row stride (bucket-major)
#define BCAP 4096                // per-bucket LDS segment cap (mean 3131, +17 sigma)

typedef int   vint4   __attribute__((ext_vector_type(4)));
typedef float vfloat4 __attribute__((ext_vector_type(4)));

__device__ __forceinline__ float leaky(float v) { return v >= 0.f ? v : NEG_SLOPE * v; }

// ---------- P0: per-block bucket histogram (bucket-major output) ----------
__global__ void __launch_bounds__(256) k_hist(const int* __restrict__ ei,
                                              int* __restrict__ histT) {
    __shared__ int hist[NBKT];
    int tid = threadIdx.x;
    hist[tid] = 0;
    hist[tid + 256] = 0;
    __syncthreads();
    const vint4* dst4 = (const vint4*)(ei + N_EDGES);
    int q0 = blockIdx.x * QPB;
    for (int q = tid; q < QPB; q += 256) {
        vint4 d = __builtin_nontemporal_load(&dst4[q0 + q]);
        atomicAdd(&hist[d.x / BDIV], 1);
        atomicAdd(&hist[d.y / BDIV], 1);
        atomicAdd(&hist[d.z / BDIV], 1);
        atomicAdd(&hist[d.w / BDIV], 1);
    }
    __syncthreads();
    histT[tid * PBS + blockIdx.x] = hist[tid];
    histT[(tid + 256) * PBS + blockIdx.x] = hist[tid + 256];
}

// ---------- P1a: per-bucket row scan (512 blocks) ----------
__global__ void __launch_bounds__(512) k_rowscan(const int* __restrict__ histT,
                                                 int* __restrict__ offT,
                                                 int* __restrict__ btot) {
    __shared__ int sm[512];
    int b = blockIdx.x, tid = threadIdx.x;
    int v = (tid < PB) ? histT[b * PBS + tid] : 0;
    sm[tid] = v;
    __syncthreads();
    for (int off = 1; off < 512; off <<= 1) {
        int t = (tid >= off) ? sm[tid - off] : 0;
        __syncthreads();
        sm[tid] += t;
        __syncthreads();
    }
    if (tid < PB) offT[b * PBS + tid] = sm[tid] - v;   // exclusive, contiguous write
    if (tid == 511) btot[b] = sm[511];
}

// ---------- P1b: bucket-base prefix (1 block) + fused attention consts ----------
// consts[0..7] cS1[r][h]; [8..15] cD1[r][h]; [16..19] cE1[h]
__global__ void __launch_bounds__(512) k_bprefix(const int* __restrict__ btot,
                                                 int* __restrict__ bbase,
                                                 int* __restrict__ bcnt,
                                                 const float* __restrict__ W1,
                                                 const float* __restrict__ attS1,
                                                 const float* __restrict__ attD1,
                                                 const float* __restrict__ We1,
                                                 const float* __restrict__ attE1,
                                                 float* __restrict__ consts) {
    __shared__ int sm[512];
    int tid = threadIdx.x;
    if (tid < 8) {
        int r = tid >> 2, h = tid & 3;
        float s = 0.f;
        for (int c = 0; c < 32; ++c) s += W1[r * 128 + h * 32 + c] * attS1[h * 32 + c];
        consts[tid] = s;
    } else if (tid < 16) {
        int u = tid - 8, r = u >> 2, h = u & 3;
        float s = 0.f;
        for (int c = 0; c < 32; ++c) s += W1[r * 128 + h * 32 + c] * attD1[h * 32 + c];
        consts[tid] = s;
    } else if (tid < 20) {
        int h = tid - 16;
        float s = 0.f;
        for (int c = 0; c < 32; ++c) s += We1[h * 32 + c] * attE1[h * 32 + c];
        consts[tid] = s;
    }
    int v = btot[tid];
    sm[tid] = v;
    __syncthreads();
    for (int off = 1; off < 512; off <<= 1) {
        int t = (tid >= off) ? sm[tid - off] : 0;
        __syncthreads();
        sm[tid] += t;
        __syncthreads();
    }
    bbase[tid] = sm[tid] - v;   // exclusive
    bcnt[tid] = v;
}

// ---------- P2: partition edges to 16B payload records, bucket-grouped ----------
// record = {src | dl<<17, w, x0[src], x1[src]}. Each (block,bucket) segment is
// single-writer & contiguous -> L2 write-combining, XCD-placement-independent.
__global__ void __launch_bounds__(512) k_part(const int* __restrict__ ei,
                                              const float* __restrict__ w,
                                              const int* __restrict__ offT,
                                              const int* __restrict__ bbase,
                                              const float* __restrict__ x,
                                              vint4* __restrict__ staging) {
    __shared__ int lcur[NBKT];
    int tid = threadIdx.x;
    lcur[tid] = offT[tid * PBS + blockIdx.x] + bbase[tid];
    __syncthreads();
    const vint4* src4 = (const vint4*)ei;
    const vint4* dst4 = (const vint4*)(ei + N_EDGES);
    const vfloat4* w4 = (const vfloat4*)w;
    int q0 = blockIdx.x * QPB;
    for (int q = tid; q < QPB; q += 512) {
        vint4 s = __builtin_nontemporal_load(&src4[q0 + q]);
        vint4 d = __builtin_nontemporal_load(&dst4[q0 + q]);
        vfloat4 ww = __builtin_nontemporal_load(&w4[q0 + q]);
#pragma unroll
        for (int j = 0; j < 4; ++j) {
            int dd = (j == 0) ? d.x : (j == 1) ? d.y : (j == 2) ? d.z : d.w;
            int ss = (j == 0) ? s.x : (j == 1) ? s.y : (j == 2) ? s.z : s.w;
            float wv = (j == 0) ? ww.x : (j == 1) ? ww.y : (j == 2) ? ww.z : ww.w;
            int b = dd / BDIV;
            int pos = atomicAdd(&lcur[b], 1);
            float2 xs = *(const float2*)(x + 2 * ss);
            vint4 r = {ss | ((dd - b * BDIV) << 17), __float_as_int(wv),
                       __float_as_int(xs.x), __float_as_int(xs.y)};
            staging[pos] = r;
        }
    }
}

// ---------- P3: fused per-bucket CSR build + layer-1 gather + MLP ----------
// Load segment once -> LDS, sort into LDS {w,x0,x1} (row-grouped), emit compact
// int2 {src,w} CSR for layer 2, then 8-lane/node gather from LDS -> h2, la.
__global__ void __launch_bounds__(512) k_bg1(const int* __restrict__ bbase,
                                             const int* __restrict__ bcnt,
                                             const vint4* __restrict__ staging,
                                             int2* __restrict__ csr2,
                                             const float* __restrict__ x,
                                             const float* __restrict__ consts,
                                             const float* __restrict__ W1,
                                             const float* __restrict__ b1,
                                             const float* __restrict__ W2,
                                             int* __restrict__ deg,
                                             int* __restrict__ rowst,
                                             float* __restrict__ h2,
                                             float* __restrict__ la) {
    __shared__ vint4 seg[BCAP];                    // 64 KB
    __shared__ float sw[BCAP], sx0[BCAP], sx1[BCAP];  // 48 KB (sorted payload)
    __shared__ int hist[256];
    __shared__ int lcur[BDIV], rowloc[BDIV], degL[BDIV];
    __shared__ float w10[132], w11[132], b1s[132], w2s[132];
    int b = blockIdx.x, tid = threadIdx.x;
    int base = bbase[b];
    int cnt = min(bcnt[b], BCAP);                  // clamp is memory-safety only
    if (tid < 256) hist[tid] = 0;
    for (int j = tid; j < 128; j += 512) {
        int jj = (j >> 5) * 33 + (j & 31);         // stride-33 pad
        w10[jj] = W1[j]; w11[jj] = W1[128 + j]; b1s[jj] = b1[j]; w2s[jj] = W2[j];
    }
    __syncthreads();
    for (int i = tid; i < cnt; i += 512) {
        vint4 r = staging[base + i];
        seg[i] = r;
        atomicAdd(&hist[r.x >> 17], 1);
    }
    __syncthreads();
    int v = (tid < 256) ? hist[tid] : 0;
    for (int off = 1; off < 256; off <<= 1) {      // inclusive scan (first 256 thr)
        int t = (tid < 256 && tid >= off) ? hist[tid - off] : 0;
        __syncthreads();
        if (tid < 256) hist[tid] += t;
        __syncthreads();
    }
    int n0 = b * BDIV;
    int nnode = min(BDIV, N_NODES - n0);
    if (tid < nnode) {
        deg[n0 + tid] = v;
        rowst[n0 + tid] = base + hist[tid] - v;
        degL[tid] = v;
        rowloc[tid] = hist[tid] - v;               // local exclusive prefix
        lcur[tid] = hist[tid] - v;
    }
    __syncthreads();
    for (int i = tid; i < cnt; i += 512) {         // scatter into row order
        vint4 r = seg[i];
        int dl = r.x >> 17;
        int pos = atomicAdd(&lcur[dl], 1);
        sw[pos] = __int_as_float(r.y);
        sx0[pos] = __int_as_float(r.z);
        sx1[pos] = __int_as_float(r.w);
        csr2[base + pos] = make_int2(r.x & 0x1FFFF, r.y);  // L2-local scatter
    }
    __syncthreads();
    // ---- layer-1 gather from LDS: 64 groups of 8 lanes, one node each ----
    float c[20];
#pragma unroll
    for (int i = 0; i < 20; ++i) c[i] = consts[i];
    int g = tid >> 3, l = tid & 7;
    for (int j = g; j < nnode; j += 64) {
        int n = n0 + j;
        int rsL = rowloc[j], d = degL[j];
        float2 xn = *(const float2*)(x + 2 * n);
        float adv[4];
#pragma unroll
        for (int h = 0; h < 4; ++h) adv[h] = xn.x * c[8 + h] + xn.y * c[12 + h];
        float s[4] = {0, 0, 0, 0}, X0[4] = {0, 0, 0, 0}, X1[4] = {0, 0, 0, 0};
        float wsum = 0.f;
        for (int k = rsL + l; k < rsL + d; k += 8) {
            float wt = sw[k], x0s = sx0[k], x1s = sx1[k];
            wsum += wt;
#pragma unroll
            for (int h = 0; h < 4; ++h) {
                float as = x0s * c[h] + x1s * c[4 + h];
                float p = __expf(leaky(as + adv[h] + wt * c[16 + h]));
                s[h] += p;
                X0[h] += p * x0s;
                X1[h] += p * x1s;
            }
        }
#pragma unroll
        for (int off = 1; off < 8; off <<= 1) {
            wsum += __shfl_xor(wsum, off);
#pragma unroll
            for (int h = 0; h < 4; ++h) {
                s[h]  += __shfl_xor(s[h], off);
                X0[h] += __shfl_xor(X0[h], off);
                X1[h] += __shfl_xor(X1[h], off);
            }
        }
        // self loop (redundant on all 8 lanes): edge attr = mean incident weight
        float lav = wsum / fmaxf((float)d, 1.f);
#pragma unroll
        for (int h = 0; h < 4; ++h) {
            float aso = xn.x * c[h] + xn.y * c[4 + h];
            float p = __expf(leaky(aso + adv[h] + lav * c[16 + h]));
            s[h] += p;
            X0[h] += p * xn.x;
            X1[h] += p * xn.y;
        }
        // MLP tail: lane l -> head l&3, channel-half l>>2 (16 ch each)
        int hh = l & 3;
        float sh  = (hh == 0) ? s[0]  : (hh == 1) ? s[1]  : (hh == 2) ? s[2]  : s[3];
        float X0h = (hh == 0) ? X0[0] : (hh == 1) ? X0[1] : (hh == 2) ? X0[2] : X0[3];
        float X1h = (hh == 0) ? X1[0] : (hh == 1) ? X1[1] : (hh == 2) ? X1[2] : X1[3];
        float inv = 1.f / (sh + 1e-16f);
        X0h *= inv;
        X1h *= inv;
        float acc = 0.f;
        int basej = hh * 33 + (l >> 2) * 16;
        for (int cc = 0; cc < 16; ++cc) {
            float vv = X0h * w10[basej + cc] + X1h * w11[basej + cc] + b1s[basej + cc];
            float el = vv > 0.f ? vv : __expf(vv) - 1.f;  // elu
            acc += el * w2s[basej + cc];
        }
        acc += __shfl_xor(acc, 1);
        acc += __shfl_xor(acc, 2);
        acc += __shfl_xor(acc, 4);
        if (l == 0) {
            h2[n] = acc;
            la[n] = lav;
        }
    }
}

// ---------- P4: layer-2 gather, 8 lanes/node, compact int2 records -> out ----------
__global__ void __launch_bounds__(256) k_gather2(const int* __restrict__ deg,
                                                 const int* __restrict__ rowst,
                                                 const int2* __restrict__ csr2,
                                                 const float* __restrict__ h2,
                                                 const float* __restrict__ la,
                                                 const float* __restrict__ attS2,
                                                 const float* __restrict__ attD2,
                                                 const float* __restrict__ We2,
                                                 const float* __restrict__ attE2,
                                                 const float* __restrict__ b2,
                                                 float* __restrict__ out) {
    int t = blockIdx.x * blockDim.x + threadIdx.x;
    int n = t >> 3, l = t & 7;
    if (n >= N_NODES) return;
    float aS = attS2[0], aD = attD2[0], cE = We2[0] * attE2[0], bb = b2[0];
    int rs = rowst[n], d = deg[n];
    float hn = h2[n];
    float hnaD = hn * aD;
    float s = 0.f, acc = 0.f;
    for (int k = rs + l; k < rs + d; k += 8) {
        int2 r = csr2[k];
        float hs = h2[r.x];
        float wt = __int_as_float(r.y);
        float p = __expf(leaky(hs * aS + hnaD + wt * cE));
        s += p;
        acc += p * hs;
    }
#pragma unroll
    for (int off = 1; off < 8; off <<= 1) {
        s   += __shfl_xor(s, off);
        acc += __shfl_xor(acc, off);
    }
    float p = __expf(leaky(hn * aS + hnaD + la[n] * cE));
    s += p;
    acc += p * hn;
    if (l == 0) out[n] = acc / (s + 1e-16f) + bb;
}

extern "C" void kernel_launch(void* const* d_in, const int* in_sizes, int n_in,
                              void* d_out, int out_size, void* d_ws, size_t ws_size,
                              hipStream_t stream) {
    const float* x     = (const float*)d_in[0];
    const int*   ei    = (const int*)d_in[1];
    const float* w     = (const float*)d_in[2];
    const float* W1    = (const float*)d_in[3];
    const float* attS1 = (const float*)d_in[4];
    const float* attD1 = (const float*)d_in[5];
    const float* We1   = (const float*)d_in[6];
    const float* attE1 = (const float*)d_in[7];
    const float* b1    = (const float*)d_in[8];
    const float* W2    = (const float*)d_in[9];
    const float* attS2 = (const float*)d_in[10];
    const float* attD2 = (const float*)d_in[11];
    const float* We2   = (const float*)d_in[12];
    const float* attE2 = (const float*)d_in[13];
    const float* b2    = (const float*)d_in[14];
    float* out = (float*)d_out;

    const size_t N = N_NODES;

    // workspace layout (~42 MB; ws_size ~268 MB per harness fill; no zero-init)
    int*   histT   = (int*)d_ws;                      // NBKT*PBS
    int*   offT    = histT + NBKT * PBS;              // NBKT*PBS (bucket-major)
    int*   btot    = offT + NBKT * PBS;               // 512
    int*   bbase   = btot + NBKT;                     // 512
    int*   bcnt    = bbase + NBKT;                    // 512
    float* consts  = (float*)(bcnt + NBKT);           // 32
    vint4* staging = (vint4*)(consts + 32);           // E * 16B (16B-aligned)
    int2*  csr2    = (int2*)(staging + N_EDGES);      // E * 8B
    int*   deg     = (int*)(csr2 + N_EDGES);          // N
    int*   rowst   = deg + N;                         // N
    float* h2      = (float*)(rowst + N);             // N
    float* la      = h2 + N;                          // N

    k_hist<<<PB, 256, 0, stream>>>(ei, histT);
    k_rowscan<<<NBKT, 512, 0, stream>>>(histT, offT, btot);
    k_bprefix<<<1, 512, 0, stream>>>(btot, bbase, bcnt, W1, attS1, attD1, We1,
                                     attE1, consts);
    k_part<<<PB, 512, 0, stream>>>(ei, w, offT, bbase, x, staging);
    k_bg1<<<NUSED, 512, 0, stream>>>(bbase, bcnt, staging, csr2, x, consts,
                                     W1, b1, W2, deg, rowst, h2, la);
    k_gather2<<<(8 * N_NODES + 255) / 256, 256, 0, stream>>>(deg, rowst, csr2, h2, la,
                                                             attS2, attD2, We2, attE2,
                                                             b2, out);
}

// Round 14
// 165.241 us; speedup vs baseline: 1.0881x; 1.0881x over previous
//
#include <hip/hip_runtime.h>

#define N_NODES 100000
#define N_EDGES 1600000
#define NQUAD (N_EDGES / 4)      // 400000
#define NEG_SLOPE 0.2f

#define NBKT 512                 // dst buckets (510 populated + tail)
#define BDIV 196                 // nodes per bucket
#define NUSED 511                // bucket blocks launched
#define PB 500                   // partition blocks
#define QPB (NQUAD / PB)         // 800 quads = 3200 edges per partition block
#define PBS 512                  // histT/offT row stride (bucket-major)
#define BCAP 3584                // per-bucket LDS segment cap (mean 3136, sd 56: +8 sigma)

typedef int   vint4   __attribute__((ext_vector_type(4)));
typedef int   vint2   __attribute__((ext_vector_type(2)));
typedef float vfloat4 __attribute__((ext_vector_type(4)));

__device__ __forceinline__ float leaky(float v) { return v >= 0.f ? v : NEG_SLOPE * v; }

// ---------- P0: per-block bucket histogram (bucket-major output) ----------
__global__ void __launch_bounds__(256) k_hist(const int* __restrict__ ei,
                                              int* __restrict__ histT) {
    __shared__ int hist[NBKT];
    int tid = threadIdx.x;
    hist[tid] = 0;
    hist[tid + 256] = 0;
    __syncthreads();
    const vint4* dst4 = (const vint4*)(ei + N_EDGES);
    int q0 = blockIdx.x * QPB;
    for (int q = tid; q < QPB; q += 256) {
        vint4 d = __builtin_nontemporal_load(&dst4[q0 + q]);
        atomicAdd(&hist[d.x / BDIV], 1);
        atomicAdd(&hist[d.y / BDIV], 1);
        atomicAdd(&hist[d.z / BDIV], 1);
        atomicAdd(&hist[d.w / BDIV], 1);
    }
    __syncthreads();
    histT[tid * PBS + blockIdx.x] = hist[tid];
    histT[(tid + 256) * PBS + blockIdx.x] = hist[tid + 256];
}

// ---------- P1a: per-bucket row scan (512 blocks) ----------
__global__ void __launch_bounds__(512) k_rowscan(const int* __restrict__ histT,
                                                 int* __restrict__ offT,
                                                 int* __restrict__ btot) {
    __shared__ int sm[512];
    int b = blockIdx.x, tid = threadIdx.x;
    int v = (tid < PB) ? histT[b * PBS + tid] : 0;
    sm[tid] = v;
    __syncthreads();
    for (int off = 1; off < 512; off <<= 1) {
        int t = (tid >= off) ? sm[tid - off] : 0;
        __syncthreads();
        sm[tid] += t;
        __syncthreads();
    }
    if (tid < PB) offT[b * PBS + tid] = sm[tid] - v;   // exclusive, contiguous write
    if (tid == 511) btot[b] = sm[511];
}

// ---------- P1b: bucket-base prefix (1 block) + fused attention consts ----------
// consts[0..7] cS1[r][h]; [8..15] cD1[r][h]; [16..19] cE1[h]
__global__ void __launch_bounds__(512) k_bprefix(const int* __restrict__ btot,
                                                 int* __restrict__ bbase,
                                                 int* __restrict__ bcnt,
                                                 const float* __restrict__ W1,
                                                 const float* __restrict__ attS1,
                                                 const float* __restrict__ attD1,
                                                 const float* __restrict__ We1,
                                                 const float* __restrict__ attE1,
                                                 float* __restrict__ consts) {
    __shared__ int sm[512];
    int tid = threadIdx.x;
    if (tid < 8) {
        int r = tid >> 2, h = tid & 3;
        float s = 0.f;
        for (int c = 0; c < 32; ++c) s += W1[r * 128 + h * 32 + c] * attS1[h * 32 + c];
        consts[tid] = s;
    } else if (tid < 16) {
        int u = tid - 8, r = u >> 2, h = u & 3;
        float s = 0.f;
        for (int c = 0; c < 32; ++c) s += W1[r * 128 + h * 32 + c] * attD1[h * 32 + c];
        consts[tid] = s;
    } else if (tid < 20) {
        int h = tid - 16;
        float s = 0.f;
        for (int c = 0; c < 32; ++c) s += We1[h * 32 + c] * attE1[h * 32 + c];
        consts[tid] = s;
    }
    int v = btot[tid];
    sm[tid] = v;
    __syncthreads();
    for (int off = 1; off < 512; off <<= 1) {
        int t = (tid >= off) ? sm[tid - off] : 0;
        __syncthreads();
        sm[tid] += t;
        __syncthreads();
    }
    bbase[tid] = sm[tid] - v;   // exclusive
    bcnt[tid] = v;
}

// ---------- P2: partition edges to 8B records {src|dl<<17, w}, bucket-grouped ----------
// Each (block,bucket) segment is single-writer & contiguous -> L2 write-combining.
__global__ void __launch_bounds__(512) k_part(const int* __restrict__ ei,
                                              const float* __restrict__ w,
                                              const int* __restrict__ offT,
                                              const int* __restrict__ bbase,
                                              int2* __restrict__ staging) {
    __shared__ int lcur[NBKT];
    int tid = threadIdx.x;
    lcur[tid] = offT[tid * PBS + blockIdx.x] + bbase[tid];
    __syncthreads();
    const vint4* src4 = (const vint4*)ei;
    const vint4* dst4 = (const vint4*)(ei + N_EDGES);
    const vfloat4* w4 = (const vfloat4*)w;
    int q0 = blockIdx.x * QPB;
    for (int q = tid; q < QPB; q += 512) {
        vint4 s = __builtin_nontemporal_load(&src4[q0 + q]);
        vint4 d = __builtin_nontemporal_load(&dst4[q0 + q]);
        vfloat4 ww = __builtin_nontemporal_load(&w4[q0 + q]);
#pragma unroll
        for (int j = 0; j < 4; ++j) {
            int dd = (j == 0) ? d.x : (j == 1) ? d.y : (j == 2) ? d.z : d.w;
            int ss = (j == 0) ? s.x : (j == 1) ? s.y : (j == 2) ? s.z : s.w;
            float wv = (j == 0) ? ww.x : (j == 1) ? ww.y : (j == 2) ? ww.z : ww.w;
            int b = dd / BDIV;
            int pos = atomicAdd(&lcur[b], 1);
            staging[pos] = make_int2(ss | ((dd - b * BDIV) << 17), __float_as_int(wv));
        }
    }
}

// ---------- P3: fused per-bucket CSR sort + layer-1 gather + MLP ----------
// LDS holds only the int2 segment (~34 KB total -> multiple blocks/CU). Sorted
// records go straight to csr2 (this CU's L2, keeps dl bits); layer-1 gathers
// from the L2-hot csr2 + x[src] (L2-resident).
__global__ void __launch_bounds__(512) k_bg1(const int* __restrict__ bbase,
                                             const int* __restrict__ bcnt,
                                             const int2* __restrict__ staging,
                                             int2* __restrict__ csr2,
                                             const float* __restrict__ x,
                                             const float* __restrict__ consts,
                                             const float* __restrict__ W1,
                                             const float* __restrict__ b1,
                                             const float* __restrict__ W2,
                                             int* __restrict__ deg,
                                             int* __restrict__ rowst,
                                             float* __restrict__ h2,
                                             float* __restrict__ la) {
    __shared__ vint2 seg[BCAP];                    // 28.7 KB
    __shared__ int hist[256];
    __shared__ int lcur[BDIV], rowloc[BDIV], degL[BDIV];
    __shared__ float w10[132], w11[132], b1s[132], w2s[132];
    int b = blockIdx.x, tid = threadIdx.x;
    int base = bbase[b];
    int cnt = min(bcnt[b], BCAP);                  // clamp is memory-safety only
    if (tid < 256) hist[tid] = 0;
    for (int j = tid; j < 128; j += 512) {
        int jj = (j >> 5) * 33 + (j & 31);         // stride-33 pad
        w10[jj] = W1[j]; w11[jj] = W1[128 + j]; b1s[jj] = b1[j]; w2s[jj] = W2[j];
    }
    __syncthreads();
    const vint2* st2 = (const vint2*)staging;
    for (int i = tid; i < cnt; i += 512) {
        vint2 r = st2[base + i];
        seg[i] = r;
        atomicAdd(&hist[r.x >> 17], 1);
    }
    __syncthreads();
    int v = (tid < 256) ? hist[tid] : 0;
    for (int off = 1; off < 256; off <<= 1) {      // inclusive scan (first 256 thr)
        int t = (tid < 256 && tid >= off) ? hist[tid - off] : 0;
        __syncthreads();
        if (tid < 256) hist[tid] += t;
        __syncthreads();
    }
    int n0 = b * BDIV;
    int nnode = min(BDIV, N_NODES - n0);
    if (tid < nnode) {
        deg[n0 + tid] = v;
        rowst[n0 + tid] = base + hist[tid] - v;
        degL[tid] = v;
        rowloc[tid] = hist[tid] - v;               // local exclusive prefix
        lcur[tid] = hist[tid] - v;
    }
    __syncthreads();
    for (int i = tid; i < cnt; i += 512) {         // sorted scatter (L2-local)
        vint2 r = seg[i];
        int pos = atomicAdd(&lcur[r.x >> 17], 1);
        csr2[base + pos] = make_int2(r.x, r.y);    // keep dl bits; readers mask
    }
    __syncthreads();
    // ---- layer-1 gather from L2-hot csr2: 64 groups of 8 lanes ----
    float c[20];
#pragma unroll
    for (int i = 0; i < 20; ++i) c[i] = consts[i];
    int g = tid >> 3, l = tid & 7;
    for (int j = g; j < nnode; j += 64) {
        int n = n0 + j;
        int rsL = base + rowloc[j], d = degL[j];
        float2 xn = *(const float2*)(x + 2 * n);
        float adv[4];
#pragma unroll
        for (int h = 0; h < 4; ++h) adv[h] = xn.x * c[8 + h] + xn.y * c[12 + h];
        float s[4] = {0, 0, 0, 0}, X0[4] = {0, 0, 0, 0}, X1[4] = {0, 0, 0, 0};
        float wsum = 0.f;
        for (int k = rsL + l; k < rsL + d; k += 8) {
            int2 r = csr2[k];
            float wt = __int_as_float(r.y);
            float2 xs = *(const float2*)(x + 2 * (r.x & 0x1FFFF));
            wsum += wt;
#pragma unroll
            for (int h = 0; h < 4; ++h) {
                float as = xs.x * c[h] + xs.y * c[4 + h];
                float p = __expf(leaky(as + adv[h] + wt * c[16 + h]));
                s[h] += p;
                X0[h] += p * xs.x;
                X1[h] += p * xs.y;
            }
        }
#pragma unroll
        for (int off = 1; off < 8; off <<= 1) {
            wsum += __shfl_xor(wsum, off);
#pragma unroll
            for (int h = 0; h < 4; ++h) {
                s[h]  += __shfl_xor(s[h], off);
                X0[h] += __shfl_xor(X0[h], off);
                X1[h] += __shfl_xor(X1[h], off);
            }
        }
        // self loop (redundant on all 8 lanes): edge attr = mean incident weight
        float lav = wsum / fmaxf((float)d, 1.f);
#pragma unroll
        for (int h = 0; h < 4; ++h) {
            float aso = xn.x * c[h] + xn.y * c[4 + h];
            float p = __expf(leaky(aso + adv[h] + lav * c[16 + h]));
            s[h] += p;
            X0[h] += p * xn.x;
            X1[h] += p * xn.y;
        }
        // MLP tail: lane l -> head l&3, channel-half l>>2 (16 ch each)
        int hh = l & 3;
        float sh  = (hh == 0) ? s[0]  : (hh == 1) ? s[1]  : (hh == 2) ? s[2]  : s[3];
        float X0h = (hh == 0) ? X0[0] : (hh == 1) ? X0[1] : (hh == 2) ? X0[2] : X0[3];
        float X1h = (hh == 0) ? X1[0] : (hh == 1) ? X1[1] : (hh == 2) ? X1[2] : X1[3];
        float inv = 1.f / (sh + 1e-16f);
        X0h *= inv;
        X1h *= inv;
        float acc = 0.f;
        int basej = hh * 33 + (l >> 2) * 16;
        for (int cc = 0; cc < 16; ++cc) {
            float vv = X0h * w10[basej + cc] + X1h * w11[basej + cc] + b1s[basej + cc];
            float el = vv > 0.f ? vv : __expf(vv) - 1.f;  // elu
            acc += el * w2s[basej + cc];
        }
        acc += __shfl_xor(acc, 1);
        acc += __shfl_xor(acc, 2);
        acc += __shfl_xor(acc, 4);
        if (l == 0) {
            h2[n] = acc;
            la[n] = lav;
        }
    }
}

// ---------- P4: layer-2 gather, 8 lanes/node -> out ----------
__global__ void __launch_bounds__(256) k_gather2(const int* __restrict__ deg,
                                                 const int* __restrict__ rowst,
                                                 const int2* __restrict__ csr2,
                                                 const float* __restrict__ h2,
                                                 const float* __restrict__ la,
                                                 const float* __restrict__ attS2,
                                                 const float* __restrict__ attD2,
                                                 const float* __restrict__ We2,
                                                 const float* __restrict__ attE2,
                                                 const float* __restrict__ b2,
                                                 float* __restrict__ out) {
    int t = blockIdx.x * blockDim.x + threadIdx.x;
    int n = t >> 3, l = t & 7;
    if (n >= N_NODES) return;
    float aS = attS2[0], aD = attD2[0], cE = We2[0] * attE2[0], bb = b2[0];
    int rs = rowst[n], d = deg[n];
    float hn = h2[n];
    float hnaD = hn * aD;
    float s = 0.f, acc = 0.f;
    for (int k = rs + l; k < rs + d; k += 8) {
        int2 r = csr2[k];
        float hs = h2[r.x & 0x1FFFF];
        float wt = __int_as_float(r.y);
        float p = __expf(leaky(hs * aS + hnaD + wt * cE));
        s += p;
        acc += p * hs;
    }
#pragma unroll
    for (int off = 1; off < 8; off <<= 1) {
        s   += __shfl_xor(s, off);
        acc += __shfl_xor(acc, off);
    }
    float p = __expf(leaky(hn * aS + hnaD + la[n] * cE));
    s += p;
    acc += p * hn;
    if (l == 0) out[n] = acc / (s + 1e-16f) + bb;
}

extern "C" void kernel_launch(void* const* d_in, const int* in_sizes, int n_in,
                              void* d_out, int out_size, void* d_ws, size_t ws_size,
                              hipStream_t stream) {
    const float* x     = (const float*)d_in[0];
    const int*   ei    = (const int*)d_in[1];
    const float* w     = (const float*)d_in[2];
    const float* W1    = (const float*)d_in[3];
    const float* attS1 = (const float*)d_in[4];
    const float* attD1 = (const float*)d_in[5];
    const float* We1   = (const float*)d_in[6];
    const float* attE1 = (const float*)d_in[7];
    const float* b1    = (const float*)d_in[8];
    const float* W2    = (const float*)d_in[9];
    const float* attS2 = (const float*)d_in[10];
    const float* attD2 = (const float*)d_in[11];
    const float* We2   = (const float*)d_in[12];
    const float* attE2 = (const float*)d_in[13];
    const float* b2    = (const float*)d_in[14];
    float* out = (float*)d_out;

    const size_t N = N_NODES;

    // workspace layout (~30 MB; ws_size ~268 MB; no zero-init needed)
    int*   histT   = (int*)d_ws;                      // NBKT*PBS
    int*   offT    = histT + NBKT * PBS;              // NBKT*PBS (bucket-major)
    int*   btot    = offT + NBKT * PBS;               // 512
    int*   bbase   = btot + NBKT;                     // 512
    int*   bcnt    = bbase + NBKT;                    // 512
    float* consts  = (float*)(bcnt + NBKT);           // 32
    int2*  staging = (int2*)(consts + 32);            // E * 8B
    int2*  csr2    = staging + N_EDGES;               // E * 8B
    int*   deg     = (int*)(csr2 + N_EDGES);          // N
    int*   rowst   = deg + N;                         // N
    float* h2      = (float*)(rowst + N);             // N
    float* la      = h2 + N;                          // N

    k_hist<<<PB, 256, 0, stream>>>(ei, histT);
    k_rowscan<<<NBKT, 512, 0, stream>>>(histT, offT, btot);
    k_bprefix<<<1, 512, 0, stream>>>(btot, bbase, bcnt, W1, attS1, attD1, We1,
                                     attE1, consts);
    k_part<<<PB, 512, 0, stream>>>(ei, w, offT, bbase, staging);
    k_bg1<<<NUSED, 512, 0, stream>>>(bbase, bcnt, staging, csr2, x, consts,
                                     W1, b1, W2, deg, rowst, h2, la);
    k_gather2<<<(8 * N_NODES + 255) / 256, 256, 0, stream>>>(deg, rowst, csr2, h2, la,
                                                             attS2, attD2, We2, attE2,
                                                             b2, out);
}

// Round 15
// 162.217 us; speedup vs baseline: 1.1084x; 1.0186x over previous
//
#include <hip/hip_runtime.h>

#define N_NODES 100000
#define N_EDGES 1600000
#define NQUAD (N_EDGES / 4)      // 400000
#define NEG_SLOPE 0.2f

#define NBKT 512                 // dst buckets (510 populated + tail)
#define BDIV 196                 // nodes per bucket
#define NUSED 511                // bucket blocks launched
#define PB 500                   // partition blocks
#define QPB (NQUAD / PB)         // 800 quads = 3200 edges per partition block
#define PBS 512                  // histT/offT row stride (bucket-major)
#define BCAP 3584                // per-bucket LDS segment cap (mean 3136, sd 56: +8 sigma)

typedef int   vint4   __attribute__((ext_vector_type(4)));
typedef int   vint2   __attribute__((ext_vector_type(2)));
typedef float vfloat4 __attribute__((ext_vector_type(4)));

__device__ __forceinline__ float leaky(float v) { return v >= 0.f ? v : NEG_SLOPE * v; }

// ---------- P0: per-block bucket histogram (bucket-major output) ----------
__global__ void __launch_bounds__(256) k_hist(const int* __restrict__ ei,
                                              int* __restrict__ histT) {
    __shared__ int hist[NBKT];
    int tid = threadIdx.x;
    hist[tid] = 0;
    hist[tid + 256] = 0;
    __syncthreads();
    const vint4* dst4 = (const vint4*)(ei + N_EDGES);
    int q0 = blockIdx.x * QPB;
    for (int q = tid; q < QPB; q += 256) {
        vint4 d = __builtin_nontemporal_load(&dst4[q0 + q]);
        atomicAdd(&hist[d.x / BDIV], 1);
        atomicAdd(&hist[d.y / BDIV], 1);
        atomicAdd(&hist[d.z / BDIV], 1);
        atomicAdd(&hist[d.w / BDIV], 1);
    }
    __syncthreads();
    histT[tid * PBS + blockIdx.x] = hist[tid];
    histT[(tid + 256) * PBS + blockIdx.x] = hist[tid + 256];
}

// ---------- P1a: per-bucket row scan (512 blocks) ----------
__global__ void __launch_bounds__(512) k_rowscan(const int* __restrict__ histT,
                                                 int* __restrict__ offT,
                                                 int* __restrict__ btot) {
    __shared__ int sm[512];
    int b = blockIdx.x, tid = threadIdx.x;
    int v = (tid < PB) ? histT[b * PBS + tid] : 0;
    sm[tid] = v;
    __syncthreads();
    for (int off = 1; off < 512; off <<= 1) {
        int t = (tid >= off) ? sm[tid - off] : 0;
        __syncthreads();
        sm[tid] += t;
        __syncthreads();
    }
    if (tid < PB) offT[b * PBS + tid] = sm[tid] - v;   // exclusive, contiguous write
    if (tid == 511) btot[b] = sm[511];
}

// ---------- P1b: bucket-base prefix (1 block) + fused attention consts ----------
// consts[0..7] cS1[r][h]; [8..15] cD1[r][h]; [16..19] cE1[h]
__global__ void __launch_bounds__(512) k_bprefix(const int* __restrict__ btot,
                                                 int* __restrict__ bbase,
                                                 int* __restrict__ bcnt,
                                                 const float* __restrict__ W1,
                                                 const float* __restrict__ attS1,
                                                 const float* __restrict__ attD1,
                                                 const float* __restrict__ We1,
                                                 const float* __restrict__ attE1,
                                                 float* __restrict__ consts) {
    __shared__ int sm[512];
    int tid = threadIdx.x;
    if (tid < 8) {
        int r = tid >> 2, h = tid & 3;
        float s = 0.f;
        for (int c = 0; c < 32; ++c) s += W1[r * 128 + h * 32 + c] * attS1[h * 32 + c];
        consts[tid] = s;
    } else if (tid < 16) {
        int u = tid - 8, r = u >> 2, h = u & 3;
        float s = 0.f;
        for (int c = 0; c < 32; ++c) s += W1[r * 128 + h * 32 + c] * attD1[h * 32 + c];
        consts[tid] = s;
    } else if (tid < 20) {
        int h = tid - 16;
        float s = 0.f;
        for (int c = 0; c < 32; ++c) s += We1[h * 32 + c] * attE1[h * 32 + c];
        consts[tid] = s;
    }
    int v = btot[tid];
    sm[tid] = v;
    __syncthreads();
    for (int off = 1; off < 512; off <<= 1) {
        int t = (tid >= off) ? sm[tid - off] : 0;
        __syncthreads();
        sm[tid] += t;
        __syncthreads();
    }
    bbase[tid] = sm[tid] - v;   // exclusive
    bcnt[tid] = v;
}

// ---------- P2: partition edges to 8B records {src|dl<<17, w}, bucket-grouped ----------
// Each (block,bucket) segment is single-writer & contiguous -> L2 write-combining.
__global__ void __launch_bounds__(512) k_part(const int* __restrict__ ei,
                                              const float* __restrict__ w,
                                              const int* __restrict__ offT,
                                              const int* __restrict__ bbase,
                                              int2* __restrict__ staging) {
    __shared__ int lcur[NBKT];
    int tid = threadIdx.x;
    lcur[tid] = offT[tid * PBS + blockIdx.x] + bbase[tid];
    __syncthreads();
    const vint4* src4 = (const vint4*)ei;
    const vint4* dst4 = (const vint4*)(ei + N_EDGES);
    const vfloat4* w4 = (const vfloat4*)w;
    int q0 = blockIdx.x * QPB;
    for (int q = tid; q < QPB; q += 512) {
        vint4 s = __builtin_nontemporal_load(&src4[q0 + q]);
        vint4 d = __builtin_nontemporal_load(&dst4[q0 + q]);
        vfloat4 ww = __builtin_nontemporal_load(&w4[q0 + q]);
#pragma unroll
        for (int j = 0; j < 4; ++j) {
            int dd = (j == 0) ? d.x : (j == 1) ? d.y : (j == 2) ? d.z : d.w;
            int ss = (j == 0) ? s.x : (j == 1) ? s.y : (j == 2) ? s.z : s.w;
            float wv = (j == 0) ? ww.x : (j == 1) ? ww.y : (j == 2) ? ww.z : ww.w;
            int b = dd / BDIV;
            int pos = atomicAdd(&lcur[b], 1);
            staging[pos] = make_int2(ss | ((dd - b * BDIV) << 17), __float_as_int(wv));
        }
    }
}

// ---------- P3: fused per-bucket sort (into LDS) + coalesced CSR write
//              + layer-1 gather from LDS + MLP ----------
// Two passes over the cache-hot 28KB staging segment: (A) histogram,
// (B) scatter into sorted LDS. Then (C) csr2 written LINEARLY (full lines,
// no atomics), (D) layer-1 gathered from LDS. ~34 KB LDS -> 4 blocks/CU.
__global__ void __launch_bounds__(512) k_bg1(const int* __restrict__ bbase,
                                             const int* __restrict__ bcnt,
                                             const int2* __restrict__ staging,
                                             int2* __restrict__ csr2,
                                             const float* __restrict__ x,
                                             const float* __restrict__ consts,
                                             const float* __restrict__ W1,
                                             const float* __restrict__ b1,
                                             const float* __restrict__ W2,
                                             int* __restrict__ deg,
                                             int* __restrict__ rowst,
                                             float* __restrict__ h2,
                                             float* __restrict__ la) {
    __shared__ vint2 srt[BCAP];                    // 28.7 KB sorted records
    __shared__ int hist[256];
    __shared__ int lcur[BDIV], rowloc[BDIV], degL[BDIV];
    __shared__ float w10[132], w11[132], b1s[132], w2s[132];
    int b = blockIdx.x, tid = threadIdx.x;
    int base = bbase[b];
    int cnt = min(bcnt[b], BCAP);                  // clamp is memory-safety only
    if (tid < 256) hist[tid] = 0;
    for (int j = tid; j < 128; j += 512) {
        int jj = (j >> 5) * 33 + (j & 31);         // stride-33 pad
        w10[jj] = W1[j]; w11[jj] = W1[128 + j]; b1s[jj] = b1[j]; w2s[jj] = W2[j];
    }
    __syncthreads();
    const vint2* st2 = (const vint2*)staging;
    // pass A: histogram only
    for (int i = tid; i < cnt; i += 512)
        atomicAdd(&hist[st2[base + i].x >> 17], 1);
    __syncthreads();
    int v = (tid < 256) ? hist[tid] : 0;
    for (int off = 1; off < 256; off <<= 1) {      // inclusive scan (first 256 thr)
        int t = (tid < 256 && tid >= off) ? hist[tid - off] : 0;
        __syncthreads();
        if (tid < 256) hist[tid] += t;
        __syncthreads();
    }
    int n0 = b * BDIV;
    int nnode = min(BDIV, N_NODES - n0);
    if (tid < nnode) {
        deg[n0 + tid] = v;
        rowst[n0 + tid] = base + hist[tid] - v;
        degL[tid] = v;
        rowloc[tid] = hist[tid] - v;               // local exclusive prefix
        lcur[tid] = hist[tid] - v;
    }
    __syncthreads();
    // pass B: cache-hot re-read, scatter into sorted LDS
    for (int i = tid; i < cnt; i += 512) {
        vint2 r = st2[base + i];
        int pos = atomicAdd(&lcur[r.x >> 17], 1);
        srt[pos] = r;
    }
    __syncthreads();
    // pass C: coalesced linear CSR write (keeps dl bits; readers mask)
    for (int i = tid; i < cnt; i += 512)
        csr2[base + i] = make_int2(srt[i].x, srt[i].y);
    // pass D: layer-1 gather from LDS: 64 groups of 8 lanes
    float c[20];
#pragma unroll
    for (int i = 0; i < 20; ++i) c[i] = consts[i];
    int g = tid >> 3, l = tid & 7;
    for (int j = g; j < nnode; j += 64) {
        int n = n0 + j;
        int rsL = rowloc[j], d = degL[j];
        float2 xn = *(const float2*)(x + 2 * n);
        float adv[4];
#pragma unroll
        for (int h = 0; h < 4; ++h) adv[h] = xn.x * c[8 + h] + xn.y * c[12 + h];
        float s[4] = {0, 0, 0, 0}, X0[4] = {0, 0, 0, 0}, X1[4] = {0, 0, 0, 0};
        float wsum = 0.f;
        for (int k = rsL + l; k < rsL + d; k += 8) {
            vint2 r = srt[k];
            float wt = __int_as_float(r.y);
            float2 xs = *(const float2*)(x + 2 * (r.x & 0x1FFFF));
            wsum += wt;
#pragma unroll
            for (int h = 0; h < 4; ++h) {
                float as = xs.x * c[h] + xs.y * c[4 + h];
                float p = __expf(leaky(as + adv[h] + wt * c[16 + h]));
                s[h] += p;
                X0[h] += p * xs.x;
                X1[h] += p * xs.y;
            }
        }
#pragma unroll
        for (int off = 1; off < 8; off <<= 1) {
            wsum += __shfl_xor(wsum, off);
#pragma unroll
            for (int h = 0; h < 4; ++h) {
                s[h]  += __shfl_xor(s[h], off);
                X0[h] += __shfl_xor(X0[h], off);
                X1[h] += __shfl_xor(X1[h], off);
            }
        }
        // self loop (redundant on all 8 lanes): edge attr = mean incident weight
        float lav = wsum / fmaxf((float)d, 1.f);
#pragma unroll
        for (int h = 0; h < 4; ++h) {
            float aso = xn.x * c[h] + xn.y * c[4 + h];
            float p = __expf(leaky(aso + adv[h] + lav * c[16 + h]));
            s[h] += p;
            X0[h] += p * xn.x;
            X1[h] += p * xn.y;
        }
        // MLP tail: lane l -> head l&3, channel-half l>>2 (16 ch each)
        int hh = l & 3;
        float sh  = (hh == 0) ? s[0]  : (hh == 1) ? s[1]  : (hh == 2) ? s[2]  : s[3];
        float X0h = (hh == 0) ? X0[0] : (hh == 1) ? X0[1] : (hh == 2) ? X0[2] : X0[3];
        float X1h = (hh == 0) ? X1[0] : (hh == 1) ? X1[1] : (hh == 2) ? X1[2] : X1[3];
        float inv = 1.f / (sh + 1e-16f);
        X0h *= inv;
        X1h *= inv;
        float acc = 0.f;
        int basej = hh * 33 + (l >> 2) * 16;
        for (int cc = 0; cc < 16; ++cc) {
            float vv = X0h * w10[basej + cc] + X1h * w11[basej + cc] + b1s[basej + cc];
            float el = vv > 0.f ? vv : __expf(vv) - 1.f;  // elu
            acc += el * w2s[basej + cc];
        }
        acc += __shfl_xor(acc, 1);
        acc += __shfl_xor(acc, 2);
        acc += __shfl_xor(acc, 4);
        if (l == 0) {
            h2[n] = acc;
            la[n] = lav;
        }
    }
}

// ---------- P4: layer-2 gather, 8 lanes/node -> out ----------
__global__ void __launch_bounds__(256) k_gather2(const int* __restrict__ deg,
                                                 const int* __restrict__ rowst,
                                                 const int2* __restrict__ csr2,
                                                 const float* __restrict__ h2,
                                                 const float* __restrict__ la,
                                                 const float* __restrict__ attS2,
                                                 const float* __restrict__ attD2,
                                                 const float* __restrict__ We2,
                                                 const float* __restrict__ attE2,
                                                 const float* __restrict__ b2,
                                                 float* __restrict__ out) {
    int t = blockIdx.x * blockDim.x + threadIdx.x;
    int n = t >> 3, l = t & 7;
    if (n >= N_NODES) return;
    float aS = attS2[0], aD = attD2[0], cE = We2[0] * attE2[0], bb = b2[0];
    int rs = rowst[n], d = deg[n];
    float hn = h2[n];
    float hnaD = hn * aD;
    float s = 0.f, acc = 0.f;
    for (int k = rs + l; k < rs + d; k += 8) {
        int2 r = csr2[k];
        float hs = h2[r.x & 0x1FFFF];
        float wt = __int_as_float(r.y);
        float p = __expf(leaky(hs * aS + hnaD + wt * cE));
        s += p;
        acc += p * hs;
    }
#pragma unroll
    for (int off = 1; off < 8; off <<= 1) {
        s   += __shfl_xor(s, off);
        acc += __shfl_xor(acc, off);
    }
    float p = __expf(leaky(hn * aS + hnaD + la[n] * cE));
    s += p;
    acc += p * hn;
    if (l == 0) out[n] = acc / (s + 1e-16f) + bb;
}

extern "C" void kernel_launch(void* const* d_in, const int* in_sizes, int n_in,
                              void* d_out, int out_size, void* d_ws, size_t ws_size,
                              hipStream_t stream) {
    const float* x     = (const float*)d_in[0];
    const int*   ei    = (const int*)d_in[1];
    const float* w     = (const float*)d_in[2];
    const float* W1    = (const float*)d_in[3];
    const float* attS1 = (const float*)d_in[4];
    const float* attD1 = (const float*)d_in[5];
    const float* We1   = (const float*)d_in[6];
    const float* attE1 = (const float*)d_in[7];
    const float* b1    = (const float*)d_in[8];
    const float* W2    = (const float*)d_in[9];
    const float* attS2 = (const float*)d_in[10];
    const float* attD2 = (const float*)d_in[11];
    const float* We2   = (const float*)d_in[12];
    const float* attE2 = (const float*)d_in[13];
    const float* b2    = (const float*)d_in[14];
    float* out = (float*)d_out;

    const size_t N = N_NODES;

    // workspace layout (~30 MB; ws_size ~268 MB; no zero-init needed)
    int*   histT   = (int*)d_ws;                      // NBKT*PBS
    int*   offT    = histT + NBKT * PBS;              // NBKT*PBS (bucket-major)
    int*   btot    = offT + NBKT * PBS;               // 512
    int*   bbase   = btot + NBKT;                     // 512
    int*   bcnt    = bbase + NBKT;                    // 512
    float* consts  = (float*)(bcnt + NBKT);           // 32
    int2*  staging = (int2*)(consts + 32);            // E * 8B
    int2*  csr2    = staging + N_EDGES;               // E * 8B
    int*   deg     = (int*)(csr2 + N_EDGES);          // N
    int*   rowst   = deg + N;                         // N
    float* h2      = (float*)(rowst + N);             // N
    float* la      = h2 + N;                          // N

    k_hist<<<PB, 256, 0, stream>>>(ei, histT);
    k_rowscan<<<NBKT, 512, 0, stream>>>(histT, offT, btot);
    k_bprefix<<<1, 512, 0, stream>>>(btot, bbase, bcnt, W1, attS1, attD1, We1,
                                     attE1, consts);
    k_part<<<PB, 512, 0, stream>>>(ei, w, offT, bbase, staging);
    k_bg1<<<NUSED, 512, 0, stream>>>(bbase, bcnt, staging, csr2, x, consts,
                                     W1, b1, W2, deg, rowst, h2, la);
    k_gather2<<<(8 * N_NODES + 255) / 256, 256, 0, stream>>>(deg, rowst, csr2, h2, la,
                                                             attS2, attD2, We2, attE2,
                                                             b2, out);
}